// Round 2
// baseline (240.034 us; speedup 1.0000x reference)
//
#include <hip/hip_runtime.h>
#include <hip/hip_bf16.h>
#include <stdint.h>

typedef __attribute__((ext_vector_type(8))) short bf16x8;
typedef __attribute__((ext_vector_type(4))) float f32x4;
typedef __attribute__((ext_vector_type(4))) unsigned short u16x4;

#define B_ 4
#define T_ 2048
#define C_ 1024
#define H_ 16
#define D_ 64

// round-to-nearest-even fp32 -> bf16
__device__ __forceinline__ unsigned short f2bf(float f) {
  union { float f; uint32_t u; } v; v.f = f;
  uint32_t u = v.u;
  uint32_t r = (u + 0x7FFFu + ((u >> 16) & 1u)) >> 16;
  return (unsigned short)r;
}

// async global->LDS, 16B per lane; lds dst = wave-uniform base + lane*16 [m97/m104]
__device__ __forceinline__ void gload_lds16(const unsigned short* g, short* l) {
  __builtin_amdgcn_global_load_lds((__attribute__((address_space(1))) void*)(uintptr_t)g,
                                   (__attribute__((address_space(3))) void*)l, 16, 0, 0);
}

__global__ void __launch_bounds__(256) cast_f32_bf16(const float* __restrict__ src,
                                                     unsigned short* __restrict__ dst,
                                                     int n4) {
  int i = blockIdx.x * 256 + threadIdx.x;
  if (i >= n4) return;
  float4 f = ((const float4*)src)[i];
  u16x4 o;
  o[0] = f2bf(f.x); o[1] = f2bf(f.y); o[2] = f2bf(f.z); o[3] = f2bf(f.w);
  ((u16x4*)dst)[i] = o;
}

// C = A[M,1024] * B[N,1024]^T, bf16, fp32 acc. m97 structure: 128x128 tile, BK=32,
// 4 waves 2x2 (64x64 each), global_load_lds width=16, LDS stride 32 (unpadded; lds
// dst must be wave-uniform base + lane*16). MODE 0: scatter q/k/v [B,H,T,D].
// MODE 1: fp32 store.
template <int MODE>
__global__ void __launch_bounds__(256) gemm_bt(const unsigned short* __restrict__ A,
                                               const unsigned short* __restrict__ Bm,
                                               unsigned short* __restrict__ qb,
                                               unsigned short* __restrict__ kb,
                                               unsigned short* __restrict__ vb,
                                               float* __restrict__ fo) {
  __shared__ short As[128 * 32];
  __shared__ short Bs[128 * 32];
  const int tid = threadIdx.x;
  const int bm = blockIdx.y * 128;
  const int bn = blockIdx.x * 128;
  const int w = tid >> 6;
  const int l = tid & 63;
  const int wm = w >> 1, wn = w & 1;
  const int lm = l & 15, lq = l >> 4;

  // staging: instr covers 16 rows x 32 cols; lane l -> row +(l>>2), col (l&3)*8
  const int srow = w * 16 + (l >> 2);
  const int scol = (l & 3) * 8;
  const unsigned short* gA0 = A + (size_t)(bm + srow) * 1024 + scol;
  const unsigned short* gA1 = gA0 + (size_t)64 * 1024;
  const unsigned short* gB0 = Bm + (size_t)(bn + srow) * 1024 + scol;
  const unsigned short* gB1 = gB0 + (size_t)64 * 1024;
  short* dA0 = As + w * 512;          // wave-uniform
  short* dA1 = As + 2048 + w * 512;
  short* dB0 = Bs + w * 512;
  short* dB1 = Bs + 2048 + w * 512;

  f32x4 acc[4][4];
#pragma unroll
  for (int i = 0; i < 4; i++)
#pragma unroll
    for (int j = 0; j < 4; j++) acc[i][j] = (f32x4){0.f, 0.f, 0.f, 0.f};

  for (int k0 = 0; k0 < 1024; k0 += 32) {
    __syncthreads();  // all waves done reading previous tile
    gload_lds16(gA0 + k0, dA0);
    gload_lds16(gA1 + k0, dA1);
    gload_lds16(gB0 + k0, dB0);
    gload_lds16(gB1 + k0, dB1);
    __syncthreads();  // vmcnt(0) drain + barrier -> tile visible to all waves
    bf16x8 af[4], bfr[4];
#pragma unroll
    for (int i = 0; i < 4; i++)
      af[i] = *(const bf16x8*)&As[(wm * 64 + 16 * i + lm) * 32 + 8 * lq];
#pragma unroll
    for (int j = 0; j < 4; j++)
      bfr[j] = *(const bf16x8*)&Bs[(wn * 64 + 16 * j + lm) * 32 + 8 * lq];
#pragma unroll
    for (int i = 0; i < 4; i++)
#pragma unroll
      for (int j = 0; j < 4; j++)
        acc[i][j] = __builtin_amdgcn_mfma_f32_16x16x32_bf16(af[i], bfr[j], acc[i][j], 0, 0, 0);
  }

  // C/D layout: col = lane&15, row = (lane>>4)*4 + reg  [m89/m91]
#pragma unroll
  for (int i = 0; i < 4; i++) {
#pragma unroll
    for (int j = 0; j < 4; j++) {
#pragma unroll
      for (int r = 0; r < 4; r++) {
        int m = bm + wm * 64 + 16 * i + 4 * lq + r;
        int n = bn + wn * 64 + 16 * j + lm;
        float val = acc[i][j][r];
        if (MODE == 0) {
          int which = n >> 10, rem = n & 1023;
          int h = rem >> 6, d = rem & 63;
          int b = m >> 11, t = m & 2047;
          unsigned short* dst = (which == 0) ? qb : ((which == 1) ? kb : vb);
          dst[(((size_t)(b * 16 + h)) * 2048 + t) * 64 + d] = f2bf(val);
        } else {
          fo[(size_t)m * 1024 + n] = val;
        }
      }
    }
  }
}

// V [B,H,T,D] -> Vt [B,H,D,T] via LDS 64x64 tile (stride 66 shorts: write 2-way
// aliasing free, read conflict-free, 4B-aligned rows).
__global__ void __launch_bounds__(256) transpose_v(const unsigned short* __restrict__ Vb,
                                                   unsigned short* __restrict__ Vt) {
  __shared__ unsigned short Ls[64 * 66];
  const int tid = threadIdx.x;
  const int bh = blockIdx.y;
  const int t0 = blockIdx.x * 64;
  const size_t base = (size_t)bh * (T_ * D_);
  const int d0 = (tid & 7) * 8;
  const int it = tid >> 3;  // 0..31
#pragma unroll
  for (int p = 0; p < 2; p++) {
    int t = it + 32 * p;
    bf16x8 v = *(const bf16x8*)(Vb + base + (size_t)(t0 + t) * 64 + d0);
#pragma unroll
    for (int e = 0; e < 8; e++) Ls[(d0 + e) * 66 + t] = (unsigned short)v[e];
  }
  __syncthreads();
  const int d = tid >> 2;
  const int c = tid & 3;
  uint32_t r[8];
  const uint32_t* Lw = (const uint32_t*)&Ls[d * 66 + c * 16];
#pragma unroll
  for (int wj = 0; wj < 8; wj++) r[wj] = Lw[wj];
  unsigned short* o = Vt + base + (size_t)d * T_ + t0 + c * 16;
  *(uint4*)o = *(const uint4*)&r[0];
  *(uint4*)(o + 8) = *(const uint4*)&r[4];
}

// Sliding-window causal flash attention. One wave per (b,h,16-query tile);
// 32-key chunks; online softmax base-2. Q,K [B,H,T,D]; V transposed [B,H,D,T].
__global__ void __launch_bounds__(256) attn_swa(const unsigned short* __restrict__ Qb,
                                               const unsigned short* __restrict__ Kb,
                                               const unsigned short* __restrict__ Vt,
                                               unsigned short* __restrict__ Ob) {
  __shared__ short P[4][16 * 40];
  const int wv = threadIdx.x >> 6;
  const int l = threadIdx.x & 63;
  const int wid = blockIdx.x * 4 + wv;
  const int bh = wid >> 7;
  const int t0 = (wid & 127) << 4;
  const int lm = l & 15, lq = l >> 4;
  const size_t base = (size_t)bh * (T_ * D_);

  bf16x8 aq0 = *(const bf16x8*)(Qb + base + (size_t)(t0 + lm) * 64 + 8 * lq);
  bf16x8 aq1 = *(const bf16x8*)(Qb + base + (size_t)(t0 + lm) * 64 + 32 + 8 * lq);

  float mst[4], lst[4];
  f32x4 Oa[4];
#pragma unroll
  for (int r = 0; r < 4; r++) { mst[r] = -1e30f; lst[r] = 0.f; }
#pragma unroll
  for (int jt = 0; jt < 4; jt++) Oa[jt] = (f32x4){0.f, 0.f, 0.f, 0.f};

  const float cs = 0.125f * 1.44269504f;  // scale * log2(e)
  int jstart = t0 - 128; if (jstart < 0) jstart = 0;

  for (int j0 = jstart; j0 < t0 + 16; j0 += 32) {
    f32x4 S[2];
#pragma unroll
    for (int hh = 0; hh < 2; hh++) {
      int kr = j0 + 16 * hh + lm; if (kr > T_ - 1) kr = T_ - 1;  // OOB keys masked below
      bf16x8 bk0 = *(const bf16x8*)(Kb + base + (size_t)kr * 64 + 8 * lq);
      bf16x8 bk1 = *(const bf16x8*)(Kb + base + (size_t)kr * 64 + 32 + 8 * lq);
      f32x4 s = (f32x4){0.f, 0.f, 0.f, 0.f};
      s = __builtin_amdgcn_mfma_f32_16x16x32_bf16(aq0, bk0, s, 0, 0, 0);
      s = __builtin_amdgcn_mfma_f32_16x16x32_bf16(aq1, bk1, s, 0, 0, 0);
      S[hh] = s;
    }
    float p0s[4], p1s[4], al[4];
#pragma unroll
    for (int r = 0; r < 4; r++) {
      int t = t0 + 4 * lq + r;
      int ja = j0 + lm, jb = j0 + 16 + lm;
      float s0 = ((ja <= t) && (ja + 128 >= t)) ? S[0][r] * cs : -1e30f;
      float s1 = ((jb <= t) && (jb + 128 >= t)) ? S[1][r] * cs : -1e30f;
      float m2 = fmaxf(s0, s1);
#pragma unroll
      for (int off = 1; off < 16; off <<= 1) m2 = fmaxf(m2, __shfl_xor(m2, off));
      float mn = fmaxf(mst[r], m2);
      float a = __builtin_amdgcn_exp2f(mst[r] - mn);
      float p0 = __builtin_amdgcn_exp2f(s0 - mn);
      float p1 = __builtin_amdgcn_exp2f(s1 - mn);
      float ps = p0 + p1;
#pragma unroll
      for (int off = 1; off < 16; off <<= 1) ps += __shfl_xor(ps, off);
      lst[r] = lst[r] * a + ps;
      mst[r] = mn;
      al[r] = a; p0s[r] = p0; p1s[r] = p1;
    }
#pragma unroll
    for (int jt = 0; jt < 4; jt++)
#pragma unroll
      for (int r = 0; r < 4; r++) Oa[jt][r] *= al[r];
    // P: C-layout -> LDS -> A-layout (m120); same-wave, no barrier
#pragma unroll
    for (int r = 0; r < 4; r++) {
      P[wv][(4 * lq + r) * 40 + lm] = (short)f2bf(p0s[r]);
      P[wv][(4 * lq + r) * 40 + 16 + lm] = (short)f2bf(p1s[r]);
    }
    bf16x8 pa = *(const bf16x8*)&P[wv][lm * 40 + 8 * lq];
    int tb = j0 + 8 * lq;
    if (tb > T_ - 8) tb = T_ - 8;  // whole 8-key group OOB => its P cols are 0
#pragma unroll
    for (int jt = 0; jt < 4; jt++) {
      bf16x8 vf = *(const bf16x8*)(Vt + base + (size_t)(16 * jt + lm) * T_ + tb);
      Oa[jt] = __builtin_amdgcn_mfma_f32_16x16x32_bf16(pa, vf, Oa[jt], 0, 0, 0);
    }
  }
  const int b = bh >> 4, h = bh & 15;
#pragma unroll
  for (int r = 0; r < 4; r++) {
    float inv = 1.0f / lst[r];
    int t = t0 + 4 * lq + r;
#pragma unroll
    for (int jt = 0; jt < 4; jt++) {
      int c = h * 64 + 16 * jt + lm;
      Ob[((size_t)(b * T_ + t)) * 1024 + c] = f2bf(Oa[jt][r] * inv);
    }
  }
}

extern "C" void kernel_launch(void* const* d_in, const int* in_sizes, int n_in,
                              void* d_out, int out_size, void* d_ws, size_t ws_size,
                              hipStream_t stream) {
  const float* x = (const float*)d_in[0];       // [4,2048,1024]
  const float* w_qkv = (const float*)d_in[1];   // [3072,1024]
  const float* w_out = (const float*)d_in[2];   // [1024,1024]
  float* out = (float*)d_out;

  // ws layout (~75.5 MB), with aliasing:
  //   xb: x bf16, dead after gemm<0>  -> reused as vtb
  //   vb: raw V, dead after transpose -> reused as attn output ob
  unsigned short* xb = (unsigned short*)d_ws;                // 8192*1024
  unsigned short* wqkvb = xb + (size_t)8192 * 1024;          // 3072*1024
  unsigned short* woutb = wqkvb + (size_t)3072 * 1024;       // 1024*1024
  unsigned short* qb = woutb + (size_t)1024 * 1024;          // 64*2048*64
  unsigned short* kb = qb + (size_t)64 * 2048 * 64;
  unsigned short* vb = kb + (size_t)64 * 2048 * 64;
  unsigned short* vtb = xb;
  unsigned short* ob = vb;

  cast_f32_bf16<<<8192, 256, 0, stream>>>(x, xb, 8192 * 1024 / 4);
  cast_f32_bf16<<<3072, 256, 0, stream>>>(w_qkv, wqkvb, 3072 * 1024 / 4);
  cast_f32_bf16<<<1024, 256, 0, stream>>>(w_out, woutb, 1024 * 1024 / 4);

  gemm_bt<0><<<dim3(24, 64), 256, 0, stream>>>(xb, wqkvb, qb, kb, vb, nullptr);
  transpose_v<<<dim3(32, 64), 256, 0, stream>>>(vb, vtb);
  attn_swa<<<2048, 256, 0, stream>>>(qb, kb, vtb, ob);
  gemm_bt<1><<<dim3(8, 64), 256, 0, stream>>>(ob, woutb, nullptr, nullptr, nullptr, out);
}

// Round 3
// 239.989 us; speedup vs baseline: 1.0002x; 1.0002x over previous
//
#include <hip/hip_runtime.h>
#include <hip/hip_bf16.h>
#include <stdint.h>

typedef __attribute__((ext_vector_type(8))) short bf16x8;
typedef __attribute__((ext_vector_type(4))) float f32x4;
typedef __attribute__((ext_vector_type(4))) unsigned short u16x4;

#define B_ 4
#define T_ 2048
#define C_ 1024
#define H_ 16
#define D_ 64

// round-to-nearest-even fp32 -> bf16
__device__ __forceinline__ unsigned short f2bf(float f) {
  union { float f; uint32_t u; } v; v.f = f;
  uint32_t u = v.u;
  uint32_t r = (u + 0x7FFFu + ((u >> 16) & 1u)) >> 16;
  return (unsigned short)r;
}

// async global->LDS, 16B per lane; lds dst = wave-uniform base + lane*16 [m97/m104]
__device__ __forceinline__ void gload_lds16(const unsigned short* g, short* l) {
  __builtin_amdgcn_global_load_lds((__attribute__((address_space(1))) void*)(uintptr_t)g,
                                   (__attribute__((address_space(3))) void*)l, 16, 0, 0);
}

// all three fp32->bf16 casts in one kernel (fewer launch gaps)
// x: 2097152 float4 | w_qkv: 786432 | w_out: 262144  -> 3145728 = 12288 blocks
__global__ void __launch_bounds__(256) cast3_f32_bf16(const float* __restrict__ x,
                                                      const float* __restrict__ wq,
                                                      const float* __restrict__ wo,
                                                      unsigned short* __restrict__ xb,
                                                      unsigned short* __restrict__ wqb,
                                                      unsigned short* __restrict__ wob) {
  int i = blockIdx.x * 256 + threadIdx.x;
  const float* s; unsigned short* d; int off;
  if (i < 2097152) { s = x; d = xb; off = i; }
  else if (i < 2097152 + 786432) { s = wq; d = wqb; off = i - 2097152; }
  else { s = wo; d = wob; off = i - 2883584; }
  float4 f = ((const float4*)s)[off];
  u16x4 o;
  o[0] = f2bf(f.x); o[1] = f2bf(f.y); o[2] = f2bf(f.z); o[3] = f2bf(f.w);
  ((u16x4*)d)[off] = o;
}

// C = A[M,1024] * B[N,1024]^T, bf16, fp32 acc. m97 structure: 128x128 tile, BK=32,
// 4 waves 2x2, global_load_lds width=16, unpadded LDS stride 32.
// MODE 0: scatter q/k/v [B,H,T,D]; Q pre-scaled by scale*log2e. MODE 1: fp32 store.
template <int MODE>
__global__ void __launch_bounds__(256) gemm_bt(const unsigned short* __restrict__ A,
                                               const unsigned short* __restrict__ Bm,
                                               unsigned short* __restrict__ qb,
                                               unsigned short* __restrict__ kb,
                                               unsigned short* __restrict__ vb,
                                               float* __restrict__ fo) {
  __shared__ short As[128 * 32];
  __shared__ short Bs[128 * 32];
  const int tid = threadIdx.x;
  const int bm = blockIdx.y * 128;
  const int bn = blockIdx.x * 128;
  const int w = tid >> 6;
  const int l = tid & 63;
  const int wm = w >> 1, wn = w & 1;
  const int lm = l & 15, lq = l >> 4;

  const int srow = w * 16 + (l >> 2);
  const int scol = (l & 3) * 8;
  const unsigned short* gA0 = A + (size_t)(bm + srow) * 1024 + scol;
  const unsigned short* gA1 = gA0 + (size_t)64 * 1024;
  const unsigned short* gB0 = Bm + (size_t)(bn + srow) * 1024 + scol;
  const unsigned short* gB1 = gB0 + (size_t)64 * 1024;
  short* dA0 = As + w * 512;
  short* dA1 = As + 2048 + w * 512;
  short* dB0 = Bs + w * 512;
  short* dB1 = Bs + 2048 + w * 512;

  f32x4 acc[4][4];
#pragma unroll
  for (int i = 0; i < 4; i++)
#pragma unroll
    for (int j = 0; j < 4; j++) acc[i][j] = (f32x4){0.f, 0.f, 0.f, 0.f};

  for (int k0 = 0; k0 < 1024; k0 += 32) {
    __syncthreads();
    gload_lds16(gA0 + k0, dA0);
    gload_lds16(gA1 + k0, dA1);
    gload_lds16(gB0 + k0, dB0);
    gload_lds16(gB1 + k0, dB1);
    __syncthreads();
    bf16x8 af[4], bfr[4];
#pragma unroll
    for (int i = 0; i < 4; i++)
      af[i] = *(const bf16x8*)&As[(wm * 64 + 16 * i + lm) * 32 + 8 * lq];
#pragma unroll
    for (int j = 0; j < 4; j++)
      bfr[j] = *(const bf16x8*)&Bs[(wn * 64 + 16 * j + lm) * 32 + 8 * lq];
#pragma unroll
    for (int i = 0; i < 4; i++)
#pragma unroll
      for (int j = 0; j < 4; j++)
        acc[i][j] = __builtin_amdgcn_mfma_f32_16x16x32_bf16(af[i], bfr[j], acc[i][j], 0, 0, 0);
  }

  // C/D layout: col = lane&15, row = (lane>>4)*4 + reg  [m89/m91]
#pragma unroll
  for (int i = 0; i < 4; i++) {
#pragma unroll
    for (int j = 0; j < 4; j++) {
#pragma unroll
      for (int r = 0; r < 4; r++) {
        int m = bm + wm * 64 + 16 * i + 4 * lq + r;
        int n = bn + wn * 64 + 16 * j + lm;
        float val = acc[i][j][r];
        if (MODE == 0) {
          int which = n >> 10, rem = n & 1023;
          int h = rem >> 6, d = rem & 63;
          int b = m >> 11, t = m & 2047;
          if (which == 0) val *= 0.1803368801f;  // scale * log2(e) folded into Q
          unsigned short* dst = (which == 0) ? qb : ((which == 1) ? kb : vb);
          dst[(((size_t)(b * 16 + h)) * 2048 + t) * 64 + d] = f2bf(val);
        } else {
          fo[(size_t)m * 1024 + n] = val;
        }
      }
    }
  }
}

// V [B,H,T,D] -> Vt [B,H,D,T]
__global__ void __launch_bounds__(256) transpose_v(const unsigned short* __restrict__ Vb,
                                                   unsigned short* __restrict__ Vt) {
  __shared__ unsigned short Ls[64 * 66];
  const int tid = threadIdx.x;
  const int bh = blockIdx.y;
  const int t0 = blockIdx.x * 64;
  const size_t base = (size_t)bh * (T_ * D_);
  const int d0 = (tid & 7) * 8;
  const int it = tid >> 3;
#pragma unroll
  for (int p = 0; p < 2; p++) {
    int t = it + 32 * p;
    bf16x8 v = *(const bf16x8*)(Vb + base + (size_t)(t0 + t) * 64 + d0);
#pragma unroll
    for (int e = 0; e < 8; e++) Ls[(d0 + e) * 66 + t] = (unsigned short)v[e];
  }
  __syncthreads();
  const int d = tid >> 2;
  const int c = tid & 3;
  uint32_t r[8];
  const uint32_t* Lw = (const uint32_t*)&Ls[d * 66 + c * 16];
#pragma unroll
  for (int wj = 0; wj < 8; wj++) r[wj] = Lw[wj];
  unsigned short* o = Vt + base + (size_t)d * T_ + t0 + c * 16;
  *(uint4*)o = *(const uint4*)&r[0];
  *(uint4*)(o + 8) = *(const uint4*)&r[4];
}

// Single-pass windowed attention (window <= 129 keys => 5 static 32-key chunks,
// end-aligned at t0-144). No online softmax: all QK first (full ILP), one
// mask/max/exp/sum pass, then PV. Q pre-scaled by scale*log2e.
__global__ void __launch_bounds__(256) attn_swa(const unsigned short* __restrict__ Qb,
                                               const unsigned short* __restrict__ Kb,
                                               const unsigned short* __restrict__ Vt,
                                               unsigned short* __restrict__ Ob) {
  __shared__ short P[4][5][16 * 40];
  const int wv = threadIdx.x >> 6;
  const int l = threadIdx.x & 63;
  const int wid = blockIdx.x * 4 + wv;
  const int bh = wid >> 7;
  const int t0 = (wid & 127) << 4;
  const int lm = l & 15, lq = l >> 4;
  const size_t base = (size_t)bh * (T_ * D_);

  bf16x8 aq0 = *(const bf16x8*)(Qb + base + (size_t)(t0 + lm) * 64 + 8 * lq);
  bf16x8 aq1 = *(const bf16x8*)(Qb + base + (size_t)(t0 + lm) * 64 + 32 + 8 * lq);

  const int j0b = t0 - 144;
  float sv[5][8];  // [chunk][hh*4+r]

  // QK^T: 20 independent K loads + 20 MFMAs
#pragma unroll
  for (int c = 0; c < 5; c++) {
    int j0 = j0b + 32 * c;
#pragma unroll
    for (int hh = 0; hh < 2; hh++) {
      int kr = j0 + 16 * hh + lm; if (kr < 0) kr = 0;  // clamped rows masked below
      const unsigned short* kp = Kb + base + (size_t)kr * 64;
      bf16x8 b0 = *(const bf16x8*)(kp + 8 * lq);
      bf16x8 b1 = *(const bf16x8*)(kp + 32 + 8 * lq);
      f32x4 s = (f32x4){0.f, 0.f, 0.f, 0.f};
      s = __builtin_amdgcn_mfma_f32_16x16x32_bf16(aq0, b0, s, 0, 0, 0);
      s = __builtin_amdgcn_mfma_f32_16x16x32_bf16(aq1, b1, s, 0, 0, 0);
#pragma unroll
      for (int r = 0; r < 4; r++) sv[c][hh * 4 + r] = s[r];
    }
  }

  // mask + max + exp2 + sum, one pass per row
  float lsum[4];
#pragma unroll
  for (int r = 0; r < 4; r++) {
    int t = t0 + 4 * lq + r;
    int lo = t - 128; if (lo < 0) lo = 0;
    float m2 = -1e30f;
#pragma unroll
    for (int c = 0; c < 5; c++)
#pragma unroll
      for (int hh = 0; hh < 2; hh++) {
        int j = j0b + 32 * c + 16 * hh + lm;
        float s = (j >= lo && j <= t) ? sv[c][hh * 4 + r] : -1e30f;
        sv[c][hh * 4 + r] = s;
        m2 = fmaxf(m2, s);
      }
#pragma unroll
    for (int off = 1; off < 16; off <<= 1) m2 = fmaxf(m2, __shfl_xor(m2, off));
    float ls = 0.f;
#pragma unroll
    for (int c = 0; c < 5; c++)
#pragma unroll
      for (int hh = 0; hh < 2; hh++) {
        float p = __builtin_amdgcn_exp2f(sv[c][hh * 4 + r] - m2);
        sv[c][hh * 4 + r] = p;
        ls += p;
      }
#pragma unroll
    for (int off = 1; off < 16; off <<= 1) ls += __shfl_xor(ls, off);
    lsum[r] = ls;
  }

  // P tiles: C-layout -> LDS (A-layout readback). Same-wave, no barrier.
#pragma unroll
  for (int c = 0; c < 5; c++)
#pragma unroll
    for (int r = 0; r < 4; r++)
#pragma unroll
      for (int hh = 0; hh < 2; hh++)
        P[wv][c][(4 * lq + r) * 40 + 16 * hh + lm] = (short)f2bf(sv[c][hh * 4 + r]);

  // PV: 5 chunks x 4 d-tiles, independent Vt loads
  f32x4 Oa[4];
#pragma unroll
  for (int jt = 0; jt < 4; jt++) Oa[jt] = (f32x4){0.f, 0.f, 0.f, 0.f};
#pragma unroll
  for (int c = 0; c < 5; c++) {
    bf16x8 pa = *(const bf16x8*)&P[wv][c][lm * 40 + 8 * lq];
    int tb = j0b + 32 * c + 8 * lq; if (tb < 0) tb = 0;  // clamped keys have P=0
#pragma unroll
    for (int jt = 0; jt < 4; jt++) {
      bf16x8 vf = *(const bf16x8*)(Vt + base + (size_t)(16 * jt + lm) * T_ + tb);
      Oa[jt] = __builtin_amdgcn_mfma_f32_16x16x32_bf16(pa, vf, Oa[jt], 0, 0, 0);
    }
  }

  const int b = bh >> 4, h = bh & 15;
#pragma unroll
  for (int r = 0; r < 4; r++) {
    float inv = 1.0f / lsum[r];
    int t = t0 + 4 * lq + r;
#pragma unroll
    for (int jt = 0; jt < 4; jt++) {
      int cc = h * 64 + 16 * jt + lm;
      Ob[((size_t)(b * T_ + t)) * 1024 + cc] = f2bf(Oa[jt][r] * inv);
    }
  }
}

extern "C" void kernel_launch(void* const* d_in, const int* in_sizes, int n_in,
                              void* d_out, int out_size, void* d_ws, size_t ws_size,
                              hipStream_t stream) {
  const float* x = (const float*)d_in[0];
  const float* w_qkv = (const float*)d_in[1];
  const float* w_out = (const float*)d_in[2];
  float* out = (float*)d_out;

  unsigned short* xb = (unsigned short*)d_ws;                // 8192*1024; reused as vtb
  unsigned short* wqkvb = xb + (size_t)8192 * 1024;          // 3072*1024
  unsigned short* woutb = wqkvb + (size_t)3072 * 1024;       // 1024*1024
  unsigned short* qb = woutb + (size_t)1024 * 1024;          // 64*2048*64
  unsigned short* kb = qb + (size_t)64 * 2048 * 64;
  unsigned short* vb = kb + (size_t)64 * 2048 * 64;          // reused as ob
  unsigned short* vtb = xb;
  unsigned short* ob = vb;

  cast3_f32_bf16<<<12288, 256, 0, stream>>>(x, w_qkv, w_out, xb, wqkvb, woutb);
  gemm_bt<0><<<dim3(24, 64), 256, 0, stream>>>(xb, wqkvb, qb, kb, vb, nullptr);
  transpose_v<<<dim3(32, 64), 256, 0, stream>>>(vb, vtb);
  attn_swa<<<2048, 256, 0, stream>>>(qb, kb, vtb, ob);
  gemm_bt<1><<<dim3(8, 64), 256, 0, stream>>>(ob, woutb, nullptr, nullptr, nullptr, out);
}